// Round 17
// baseline (55.243 us; speedup 1.0000x reference)
//
#include <hip/hip_runtime.h>

#define NPTS 4096
#define N0V  10242
#define EPSV 1e-5f
#define NBLK 256
#define SLOTS 16

typedef unsigned short ushortT;
typedef __attribute__((ext_vector_type(8))) short short8;
typedef __attribute__((ext_vector_type(4))) float f32x4;

__device__ __forceinline__ float fmul(float a,float b){return __fmul_rn(a,b);}
__device__ __forceinline__ float fadd(float a,float b){return __fadd_rn(a,b);}
__device__ __forceinline__ float fsub(float a,float b){return __fsub_rn(a,b);}

__device__ __forceinline__ ushortT f2bf(float x){
  unsigned u = __float_as_uint(x);
  u = (u + 0x7fffu + ((u>>16)&1u)) >> 16;
  return (ushortT)u;
}
__device__ __forceinline__ float bf2f(ushortT u){
  return __uint_as_float(((unsigned)u) << 16);
}

// ---- per-wave 16x16 MFMA tile ----
template<int NS>
__device__ __forceinline__ void tile_mm(const ushortT* xa, const ushortT* wt, int wstr,
    int li, int hi, int rt, int colg, f32x4& acc)
{
  acc = (f32x4){0.f,0.f,0.f,0.f};
  const ushortT* wbp = wt + colg*wstr + hi*8;
  const ushortT* xap = xa + (rt*16 + li)*168 + hi*8;
  #pragma unroll
  for (int s=0;s<NS;s++){
    short8 bb = *(const short8*)(wbp + s*32);
    short8 a0 = *(const short8*)(xap + s*32);
    acc = __builtin_amdgcn_mfma_f32_16x16x32_bf16(a0, bb, acc, 0,0,0);
  }
}

// ---- per-wave partial sums -> 16-slot atomicAdd ----
__device__ __forceinline__ void tile_partials(const f32x4& acc, float* __restrict__ slotL,
                                              int blk, int lane, int colg)
{
  float s1=0.f, s2=0.f;
  #pragma unroll
  for (int r=0;r<4;r++){ s1 += acc[r]; s2 = fmaf(acc[r],acc[r],s2); }
  s1 += __shfl_xor(s1,16); s1 += __shfl_xor(s1,32);
  s2 += __shfl_xor(s2,16); s2 += __shfl_xor(s2,32);
  if (lane < 16){
    float* sl = slotL + (blk & (SLOTS-1))*256;
    atomicAdd(&sl[colg], s1);
    atomicAdd(&sl[128 + colg], s2);
  }
}

// ---- compute stS/stB from 256-wide sums in red2 ----
__device__ __forceinline__ void stats_from_red2(const float* red2,
    const float* __restrict__ g, const float* __restrict__ be,
    float* stS, float* stB, int t)
{
  if (t < 128){
    float S = red2[t], Q = red2[128 + t];
    float mean = S * (1.0f/8192.0f);
    float var  = Q * (1.0f/8192.0f) - mean*mean;
    float inv  = 1.0f / __fsqrt_rn(var + EPSV);
    float sc = g[t]*inv;
    stS[t] = sc;
    stB[t] = be[t] - mean*sc;
  }
  __syncthreads();
}

// ---- stats via PLAIN slot loads (kernel-boundary sync) ----
__device__ __forceinline__ void slot_stats(const float* __restrict__ slotL,
    const float* __restrict__ g, const float* __restrict__ be,
    float* red2, float* stS, float* stB, int t)
{
  if (t < 256){
    float v = 0.f;
    #pragma unroll
    for (int s=0;s<SLOTS;s++) v += slotL[s*256 + t];
    red2[t] = v;
  }
  __syncthreads();
  stats_from_red2(red2, g, be, stS, stB, t);
}

// ---- DMA a linear bf16 weight block global->LDS (nchunks x 1KB) ----
__device__ __forceinline__ void dma_w(const ushortT* __restrict__ src, ushortT* dst,
                                      int nchunks, int w, int lane)
{
  const char* s = (const char*)src;
  char* d = (char*)dst;
  for (int i = w; i < nchunks; i += 16){
    __builtin_amdgcn_global_load_lds(
        (const __attribute__((address_space(1))) void*)(s + (size_t)i*1024 + (size_t)lane*16),
        (__attribute__((address_space(3))) void*)(d + (size_t)i*1024), 16, 0, 0);
  }
}

// ================= k_l0: scan + gather + pack wt0 + L0 MFMA + partials + y0(bf16)
//                   side jobs: zero slot1/slot2; pack W1/W2 -> global bf16 wpkg =================
__global__ __launch_bounds__(1024) void k_l0(
    const float* __restrict__ orig, const float* __restrict__ proj,
    const float* __restrict__ vertex, const int* __restrict__ nidx,
    const float* __restrict__ W0, const float* __restrict__ b0,
    const float* __restrict__ W1, const float* __restrict__ W2,
    float* __restrict__ slot0, float* __restrict__ slotZ,
    ushortT* __restrict__ wpkg, ushortT* __restrict__ y0)
{
  __shared__ __align__(16) ushortT wt[128*168];
  __shared__ __align__(16) ushortT xa[32*168];

  const int t    = threadIdx.x;
  const int blk  = blockIdx.x;
  const int lane = t & 63;
  const int w    = t >> 6;
  const int b    = blk >> 7;
  const int n0   = (blk & 127) * 32;
  const int li   = lane & 15;
  const int hi   = lane >> 4;
  const int rt   = w >> 3;
  const int colg = (w & 7)*16 + li;

  // zero slot1+slot2 (8 blocks x 1024)
  if (blk < 8) slotZ[blk*1024 + t] = 0.f;

  // pack W1/W2 -> global bf16 [2][128][136] (136 els per block; 256*136 = 34816)
  if (t < 136){
    int u = blk*136 + t;
    int L = u / 17408, q = u - L*17408;
    int o = q / 136, k = q - o*136;
    float v = 0.f;
    if (k < 128) v = (L == 0) ? W1[o*128 + k] : W2[o*128 + k];
    wpkg[u] = f2bf(v);
  }

  // pack wt0 f32->bf16 into LDS
  for (int u = t; u < 21504; u += 1024){
    int o = u/168, k = u - o*168;
    wt[u] = f2bf((k < 147) ? W0[o*147 + k] : 0.f);
  }

  // scan + gather: 2 rows per wave
  {
    float v0x=vertex[0], v0y=vertex[1], v0z=vertex[2];
    float r  = __fsqrt_rn(fadd(fadd(fmul(v0x,v0x),fmul(v0y,v0y)),fmul(v0z,v0z)));
    float rr = fmul(r,r);
    int j0 = nidx[0];
    float ax=vertex[3*j0], ay=vertex[3*j0+1], az=vertex[3*j0+2];
    float dx=fsub(v0x,ax), dy=fsub(v0y,ay), dz=fsub(v0z,az);
    float t2 = fadd(fadd(fmul(dx,dx),fmul(dy,dy)),fmul(dz,dz));

    #pragma unroll
    for (int rr_i=0; rr_i<2; rr_i++){
      const int row = w*2 + rr_i;
      const int n = n0 + row;
      const float* ob = orig + (b*19)*NPTS + n;
      float x=ob[0], y=ob[NPTS], z=ob[2*NPTS];
      float nrm = __fsqrt_rn(fadd(fadd(fmul(x,x),fmul(y,y)),fmul(z,z)));
      float s = __fdiv_rn(r,nrm);
      float px=fmul(x,s), py=fmul(y,s), pz=fmul(z,s);

      int first=0, has=0;
      for (int c0=0; c0<N0V; c0+=256){
        int m0=min(c0+lane,N0V-1), m1=min(c0+lane+64,N0V-1),
            m2=min(c0+lane+128,N0V-1), m3=min(c0+lane+192,N0V-1);
        float a0x=vertex[3*m0],a0y=vertex[3*m0+1],a0z=vertex[3*m0+2];
        float a1x=vertex[3*m1],a1y=vertex[3*m1+1],a1z=vertex[3*m1+2];
        float a2x=vertex[3*m2],a2y=vertex[3*m2+1],a2z=vertex[3*m2+2];
        float a3x=vertex[3*m3],a3y=vertex[3*m3+1],a3z=vertex[3*m3+2];
        float v20=fadd(fadd(fmul(a0x,a0x),fmul(a0y,a0y)),fmul(a0z,a0z));
        float v21=fadd(fadd(fmul(a1x,a1x),fmul(a1y,a1y)),fmul(a1z,a1z));
        float v22=fadd(fadd(fmul(a2x,a2x),fmul(a2y,a2y)),fmul(a2z,a2z));
        float v23=fadd(fadd(fmul(a3x,a3x),fmul(a3y,a3y)),fmul(a3z,a3z));
        float d0=fadd(fadd(fmul(px,a0x),fmul(py,a0y)),fmul(pz,a0z));
        float d1=fadd(fadd(fmul(px,a1x),fmul(py,a1y)),fmul(pz,a1z));
        float d2=fadd(fadd(fmul(px,a2x),fmul(py,a2y)),fmul(pz,a2z));
        float d3=fadd(fadd(fmul(px,a3x),fmul(py,a3y)),fmul(pz,a3z));
        bool h0 = (c0+lane    <N0V) && (fsub(fadd(rr,v20),fmul(2.0f,d0)) <= t2);
        bool h1 = (c0+lane+64 <N0V) && (fsub(fadd(rr,v21),fmul(2.0f,d1)) <= t2);
        bool h2 = (c0+lane+128<N0V) && (fsub(fadd(rr,v22),fmul(2.0f,d2)) <= t2);
        bool h3 = (c0+lane+192<N0V) && (fsub(fadd(rr,v23),fmul(2.0f,d3)) <= t2);
        unsigned long long bal;
        if ((bal=__ballot(h0))){ first=c0     +__builtin_ctzll(bal); has=1; break; }
        if ((bal=__ballot(h1))){ first=c0+ 64+__builtin_ctzll(bal); has=1; break; }
        if ((bal=__ballot(h2))){ first=c0+128+__builtin_ctzll(bal); has=1; break; }
        if ((bal=__ballot(h3))){ first=c0+192+__builtin_ctzll(bal); has=1; break; }
      }

      ushortT* rowp = xa + row*168;
      const float* pb = proj + (long)b*128*N0V;
      #pragma unroll
      for (int k=0;k<3;k++){
        int idx = lane + k*64;
        if (idx < 168){
          float v;
          if (idx < 19)        v = orig[(b*19+idx)*NPTS + n];
          else if (idx < 147)  v = has ? pb[(long)(idx-19)*N0V + first] : 0.0f;
          else                 v = 0.0f;
          rowp[idx] = f2bf(v);
        }
      }
    }
  }
  __syncthreads();

  f32x4 acc;
  tile_mm<5>(xa, wt, 168, li, hi, rt, colg, acc);
  float bo = b0[colg];
  #pragma unroll
  for (int r=0;r<4;r++) acc[r] += bo;
  tile_partials(acc, slot0, blk, lane, colg);
  #pragma unroll
  for (int r=0;r<4;r++)
    y0[(long)(b*4096 + n0 + rt*16 + hi*4 + r)*128 + colg] = f2bf(acc[r]);
}

// ================= k_lmid (L1): DMA wt + stats(slot0) + affine + MFMA + partials + y1 =========
__global__ __launch_bounds__(1024) void k_lmid(
    const ushortT* __restrict__ yin, const float* __restrict__ slotPrev,
    const float* __restrict__ g, const float* __restrict__ be,
    const ushortT* __restrict__ wpk, const float* __restrict__ bias,
    float* __restrict__ slotCur, ushortT* __restrict__ yout)
{
  __shared__ __align__(16) ushortT wt[128*136];
  __shared__ __align__(16) ushortT xa[32*168];
  __shared__ float red2[256];
  __shared__ float stS[128];
  __shared__ float stB[128];

  const int t    = threadIdx.x;
  const int blk  = blockIdx.x;
  const int lane = t & 63;
  const int w    = t >> 6;
  const int n0   = blk * 32;
  const int li   = lane & 15;
  const int hi   = lane >> 4;
  const int rt   = w >> 3;
  const int colg = (w & 7)*16 + li;

  dma_w(wpk, wt, 34, w, lane);                     // 34816B, overlaps everything below

  for (int u = t; u < 1280; u += 1024){            // zero xa pad cols 128..167
    int row = u/40, c = 128 + (u - row*40);
    xa[row*168 + c] = 0;
  }
  slot_stats(slotPrev, g, be, red2, stS, stB, t);

  if (t < 512){
    int row = t >> 4, c0 = (t & 15) * 8;
    short8 yv = *(const short8*)(yin + (long)(n0+row)*128 + c0);
    short8 xv;
    #pragma unroll
    for (int j=0;j<8;j++){
      float f = bf2f((ushortT)yv[j]);
      f = fmaxf(fmaf(f, stS[c0+j], stB[c0+j]), 0.f);
      xv[j] = (short)f2bf(f);
    }
    *(short8*)(xa + row*168 + c0) = xv;
  }
  __syncthreads();                                 // drains DMA (vmcnt 0) + xa ready

  f32x4 acc;
  tile_mm<4>(xa, wt, 136, li, hi, rt, colg, acc);
  float bo = bias[colg];
  #pragma unroll
  for (int r=0;r<4;r++) acc[r] += bo;
  tile_partials(acc, slotCur, blk, lane, colg);
  #pragma unroll
  for (int r=0;r<4;r++)
    yout[(long)(n0 + rt*16 + hi*4 + r)*128 + colg] = f2bf(acc[r]);
}

// ========== k_final (cooperative): L2 GEMM + partials + software barrier + stats + store ======
struct FinParams {
  const ushortT* yin; const float* slotPrev;
  const float* g1; const float* be1;
  const ushortT* wpk; const float* bias;
  float* slotCur; int* cnt;
  const float* g2; const float* be2;
  float* out;
};

__global__ __launch_bounds__(1024) void k_final(FinParams p)
{
  __shared__ __align__(16) ushortT wt[128*136];
  __shared__ __align__(16) ushortT xa[32*168];
  __shared__ float ft[32*132];
  __shared__ float red2[256];
  __shared__ float stS[128];
  __shared__ float stB[128];

  const int t    = threadIdx.x;
  const int blk  = blockIdx.x;
  const int lane = t & 63;
  const int w    = t >> 6;
  const int n0g  = blk * 32;          // global row
  const int b    = blk >> 7;
  const int n0   = (blk & 127) * 32;  // row within batch
  const int li   = lane & 15;
  const int hi   = lane >> 4;
  const int rt   = w >> 3;
  const int colg = (w & 7)*16 + li;

  dma_w(p.wpk, wt, 34, w, lane);

  for (int u = t; u < 1280; u += 1024){
    int row = u/40, c = 128 + (u - row*40);
    xa[row*168 + c] = 0;
  }
  slot_stats(p.slotPrev, p.g1, p.be1, red2, stS, stB, t);

  if (t < 512){
    int row = t >> 4, c0 = (t & 15) * 8;
    short8 yv = *(const short8*)(p.yin + (long)(n0g+row)*128 + c0);
    short8 xv;
    #pragma unroll
    for (int j=0;j<8;j++){
      float f = bf2f((ushortT)yv[j]);
      f = fmaxf(fmaf(f, stS[c0+j], stB[c0+j]), 0.f);
      xv[j] = (short)f2bf(f);
    }
    *(short8*)(xa + row*168 + c0) = xv;
  }
  __syncthreads();

  f32x4 acc;
  tile_mm<4>(xa, wt, 136, li, hi, rt, colg, acc);
  float bo = p.bias[colg];
  #pragma unroll
  for (int r=0;r<4;r++) acc[r] += bo;
  tile_partials(acc, p.slotCur, blk, lane, colg);

  // ---- software grid barrier (R10/R12-proven: relaxed counter, no fences) ----
  __syncthreads();   // vmcnt(0): this block's slot atomics globally performed
  if (t == 0){
    __hip_atomic_fetch_add(p.cnt, 1, __ATOMIC_RELAXED, __HIP_MEMORY_SCOPE_AGENT);
    while (__hip_atomic_load(p.cnt, __ATOMIC_RELAXED, __HIP_MEMORY_SCOPE_AGENT) < NBLK)
      __builtin_amdgcn_s_sleep(1);
  }
  __syncthreads();
  if (t < 256){
    float v = 0.f;
    #pragma unroll
    for (int s=0;s<SLOTS;s++)
      v += __hip_atomic_load(&p.slotCur[s*256 + t], __ATOMIC_RELAXED, __HIP_MEMORY_SCOPE_AGENT);
    red2[t] = v;
  }
  __syncthreads();
  stats_from_red2(red2, p.g2, p.be2, stS, stB, t);

  // final affine+relu from registers -> LDS transpose -> store
  {
    float ss = stS[colg], sb = stB[colg];
    #pragma unroll
    for (int r=0;r<4;r++)
      ft[(rt*16 + hi*4 + r)*132 + colg] = fmaxf(fmaf(acc[r], ss, sb), 0.f);
  }
  __syncthreads();
  {
    float* ob = p.out + (long)b*128*NPTS + n0;
    int oo = t >> 3, jj = (t & 7) * 4;
    float4 v;
    v.x = ft[(jj  )*132 + oo];
    v.y = ft[(jj+1)*132 + oo];
    v.z = ft[(jj+2)*132 + oo];
    v.w = ft[(jj+3)*132 + oo];
    *(float4*)(ob + (long)oo*NPTS + jj) = v;
  }
}

extern "C" void kernel_launch(void* const* d_in, const int* in_sizes, int n_in,
                              void* d_out, int out_size, void* d_ws, size_t ws_size,
                              hipStream_t stream)
{
  const float* orig   = (const float*)d_in[0];
  const float* proj   = (const float*)d_in[1];
  const float* vertex = (const float*)d_in[2];
  const int*   nidx   = (const int*)d_in[3];
  const float* W0 = (const float*)d_in[4];
  const float* b0 = (const float*)d_in[5];
  const float* g0 = (const float*)d_in[6];
  const float* be0= (const float*)d_in[7];
  const float* W1 = (const float*)d_in[8];
  const float* b1 = (const float*)d_in[9];
  const float* g1 = (const float*)d_in[10];
  const float* be1= (const float*)d_in[11];
  const float* W2 = (const float*)d_in[12];
  const float* b2 = (const float*)d_in[13];
  const float* g2 = (const float*)d_in[14];
  const float* be2= (const float*)d_in[15];
  float* out = (float*)d_out;

  float*   ws    = (float*)d_ws;
  float*   slot0 = ws;                        // 4096 floats
  int*     cnt   = (int*)(ws + 4096);         // 16 floats reserved
  float*   slot1 = ws + 4112;                 // 4096
  float*   slot2 = ws + 8208;                 // 4096 (contiguous with slot1 for slotZ)
  ushortT* wpkg  = (ushortT*)(ws + 12304);    // 34816 bf16 = 17408 floats
  ushortT* yA    = (ushortT*)(ws + 29712);    // 8192*128 bf16
  ushortT* yB    = yA + 8192*128;

  // zero slot0 + cnt (single small graph node); slot1/slot2 zeroed inside k_l0
  hipMemsetAsync(d_ws, 0, 4112*sizeof(float), stream);

  k_l0  <<<256, 1024, 0, stream>>>(orig, proj, vertex, nidx, W0, b0, W1, W2,
                                   slot0, slot1, wpkg, yA);
  k_lmid<<<256, 1024, 0, stream>>>(yA, slot0, g0, be0, wpkg, b1, slot1, yB);

  FinParams fp{yB, slot1, g1, be1, wpkg + 17408, b2, slot2, cnt, g2, be2, out};
  void* args[] = {(void*)&fp};
  hipLaunchCooperativeKernel((const void*)k_final, dim3(NBLK), dim3(1024), args, 0, stream);
}

// Round 18
// 30.826 us; speedup vs baseline: 1.7921x; 1.7921x over previous
//
#include <hip/hip_runtime.h>

#define NPTS 4096
#define N0V  10242
#define EPSV 1e-5f
#define SLOTS 16

typedef unsigned short ushortT;
typedef __attribute__((ext_vector_type(8))) short short8;
typedef __attribute__((ext_vector_type(4))) float f32x4;

__device__ __forceinline__ float fmul(float a,float b){return __fmul_rn(a,b);}
__device__ __forceinline__ float fadd(float a,float b){return __fadd_rn(a,b);}
__device__ __forceinline__ float fsub(float a,float b){return __fsub_rn(a,b);}

__device__ __forceinline__ ushortT f2bf(float x){
  unsigned u = __float_as_uint(x);
  u = (u + 0x7fffu + ((u>>16)&1u)) >> 16;
  return (ushortT)u;
}
__device__ __forceinline__ float bf2f(ushortT u){
  return __uint_as_float(((unsigned)u) << 16);
}

// ---- per-wave 16x16 MFMA tile ----
template<int NS>
__device__ __forceinline__ void tile_mm(const ushortT* xa, const ushortT* wt, int wstr,
    int li, int hi, int rt, int colg, f32x4& acc)
{
  acc = (f32x4){0.f,0.f,0.f,0.f};
  const ushortT* wbp = wt + colg*wstr + hi*8;
  const ushortT* xap = xa + (rt*16 + li)*168 + hi*8;
  #pragma unroll
  for (int s=0;s<NS;s++){
    short8 bb = *(const short8*)(wbp + s*32);
    short8 a0 = *(const short8*)(xap + s*32);
    acc = __builtin_amdgcn_mfma_f32_16x16x32_bf16(a0, bb, acc, 0,0,0);
  }
}

// ---- per-wave partial sums -> 16-slot atomicAdd (visibility via kernel boundary) ----
__device__ __forceinline__ void tile_partials(const f32x4& acc, float* __restrict__ slotL,
                                              int blk, int lane, int colg)
{
  float s1=0.f, s2=0.f;
  #pragma unroll
  for (int r=0;r<4;r++){ s1 += acc[r]; s2 = fmaf(acc[r],acc[r],s2); }
  s1 += __shfl_xor(s1,16); s1 += __shfl_xor(s1,32);
  s2 += __shfl_xor(s2,16); s2 += __shfl_xor(s2,32);
  if (lane < 16){
    float* sl = slotL + (blk & (SLOTS-1))*256;
    atomicAdd(&sl[colg], s1);
    atomicAdd(&sl[128 + colg], s2);
  }
}

// ---- stats from previous kernel's slots: PLAIN loads (inter-dispatch barrier = sync) ----
__device__ __forceinline__ void slot_stats(const float* __restrict__ slotL,
    const float* __restrict__ g, const float* __restrict__ be,
    float* red2, float* stS, float* stB, int t)
{
  if (t < 256){
    float v = 0.f;
    #pragma unroll
    for (int s=0;s<SLOTS;s++) v += slotL[s*256 + t];
    red2[t] = v;
  }
  __syncthreads();
  if (t < 128){
    float S = red2[t], Q = red2[128 + t];
    float mean = S * (1.0f/8192.0f);
    float var  = Q * (1.0f/8192.0f) - mean*mean;
    float inv  = 1.0f / __fsqrt_rn(var + EPSV);
    float sc = g[t]*inv;
    stS[t] = sc;
    stB[t] = be[t] - mean*sc;
  }
  __syncthreads();
}

// ---- DMA a linear bf16 weight block global->LDS (nchunks x 1KB) ----
__device__ __forceinline__ void dma_w(const ushortT* __restrict__ src, ushortT* dst,
                                      int nchunks, int w, int lane)
{
  const char* s = (const char*)src;
  char* d = (char*)dst;
  for (int i = w; i < nchunks; i += 16){
    __builtin_amdgcn_global_load_lds(
        (const __attribute__((address_space(1))) void*)(s + (size_t)i*1024 + (size_t)lane*16),
        (__attribute__((address_space(3))) void*)(d + (size_t)i*1024), 16, 0, 0);
  }
}

// ================= k_l0: scan + gather + pack wt0 + L0 MFMA + partials + y0(bf16)
//                   side jobs: zero slot1/slot2; pack W1/W2 -> global bf16 wpkg =================
__global__ __launch_bounds__(1024) void k_l0(
    const float* __restrict__ orig, const float* __restrict__ proj,
    const float* __restrict__ vertex, const int* __restrict__ nidx,
    const float* __restrict__ W0, const float* __restrict__ b0,
    const float* __restrict__ W1, const float* __restrict__ W2,
    float* __restrict__ slot0, float* __restrict__ slotZ,
    ushortT* __restrict__ wpkg, ushortT* __restrict__ y0)
{
  __shared__ __align__(16) ushortT wt[128*168];
  __shared__ __align__(16) ushortT xa[32*168];

  const int t    = threadIdx.x;
  const int blk  = blockIdx.x;
  const int lane = t & 63;
  const int w    = t >> 6;
  const int b    = blk >> 7;
  const int n0   = (blk & 127) * 32;
  const int li   = lane & 15;
  const int hi   = lane >> 4;
  const int rt   = w >> 3;
  const int colg = (w & 7)*16 + li;

  // zero slot1+slot2 (8 blocks x 1024 floats)
  if (blk < 8) slotZ[blk*1024 + t] = 0.f;

  // pack W1/W2 -> global bf16 [2][128][136] (136 els per block; 256*136 = 34816)
  if (t < 136){
    int u = blk*136 + t;
    int L = u / 17408, q = u - L*17408;
    int o = q / 136, k = q - o*136;
    float v = 0.f;
    if (k < 128) v = (L == 0) ? W1[o*128 + k] : W2[o*128 + k];
    wpkg[u] = f2bf(v);
  }

  // pack wt0 f32->bf16 into LDS
  for (int u = t; u < 21504; u += 1024){
    int o = u/168, k = u - o*168;
    wt[u] = f2bf((k < 147) ? W0[o*147 + k] : 0.f);
  }

  // scan + gather: 2 rows per wave
  {
    float v0x=vertex[0], v0y=vertex[1], v0z=vertex[2];
    float r  = __fsqrt_rn(fadd(fadd(fmul(v0x,v0x),fmul(v0y,v0y)),fmul(v0z,v0z)));
    float rr = fmul(r,r);
    int j0 = nidx[0];
    float ax=vertex[3*j0], ay=vertex[3*j0+1], az=vertex[3*j0+2];
    float dx=fsub(v0x,ax), dy=fsub(v0y,ay), dz=fsub(v0z,az);
    float t2 = fadd(fadd(fmul(dx,dx),fmul(dy,dy)),fmul(dz,dz));

    #pragma unroll
    for (int rr_i=0; rr_i<2; rr_i++){
      const int row = w*2 + rr_i;
      const int n = n0 + row;
      const float* ob = orig + (b*19)*NPTS + n;
      float x=ob[0], y=ob[NPTS], z=ob[2*NPTS];
      float nrm = __fsqrt_rn(fadd(fadd(fmul(x,x),fmul(y,y)),fmul(z,z)));
      float s = __fdiv_rn(r,nrm);
      float px=fmul(x,s), py=fmul(y,s), pz=fmul(z,s);

      int first=0, has=0;
      for (int c0=0; c0<N0V; c0+=256){
        int m0=min(c0+lane,N0V-1), m1=min(c0+lane+64,N0V-1),
            m2=min(c0+lane+128,N0V-1), m3=min(c0+lane+192,N0V-1);
        float a0x=vertex[3*m0],a0y=vertex[3*m0+1],a0z=vertex[3*m0+2];
        float a1x=vertex[3*m1],a1y=vertex[3*m1+1],a1z=vertex[3*m1+2];
        float a2x=vertex[3*m2],a2y=vertex[3*m2+1],a2z=vertex[3*m2+2];
        float a3x=vertex[3*m3],a3y=vertex[3*m3+1],a3z=vertex[3*m3+2];
        float v20=fadd(fadd(fmul(a0x,a0x),fmul(a0y,a0y)),fmul(a0z,a0z));
        float v21=fadd(fadd(fmul(a1x,a1x),fmul(a1y,a1y)),fmul(a1z,a1z));
        float v22=fadd(fadd(fmul(a2x,a2x),fmul(a2y,a2y)),fmul(a2z,a2z));
        float v23=fadd(fadd(fmul(a3x,a3x),fmul(a3y,a3y)),fmul(a3z,a3z));
        float d0=fadd(fadd(fmul(px,a0x),fmul(py,a0y)),fmul(pz,a0z));
        float d1=fadd(fadd(fmul(px,a1x),fmul(py,a1y)),fmul(pz,a1z));
        float d2=fadd(fadd(fmul(px,a2x),fmul(py,a2y)),fmul(pz,a2z));
        float d3=fadd(fadd(fmul(px,a3x),fmul(py,a3y)),fmul(pz,a3z));
        bool h0 = (c0+lane    <N0V) && (fsub(fadd(rr,v20),fmul(2.0f,d0)) <= t2);
        bool h1 = (c0+lane+64 <N0V) && (fsub(fadd(rr,v21),fmul(2.0f,d1)) <= t2);
        bool h2 = (c0+lane+128<N0V) && (fsub(fadd(rr,v22),fmul(2.0f,d2)) <= t2);
        bool h3 = (c0+lane+192<N0V) && (fsub(fadd(rr,v23),fmul(2.0f,d3)) <= t2);
        unsigned long long bal;
        if ((bal=__ballot(h0))){ first=c0     +__builtin_ctzll(bal); has=1; break; }
        if ((bal=__ballot(h1))){ first=c0+ 64+__builtin_ctzll(bal); has=1; break; }
        if ((bal=__ballot(h2))){ first=c0+128+__builtin_ctzll(bal); has=1; break; }
        if ((bal=__ballot(h3))){ first=c0+192+__builtin_ctzll(bal); has=1; break; }
      }

      ushortT* rowp = xa + row*168;
      const float* pb = proj + (long)b*128*N0V;
      #pragma unroll
      for (int k=0;k<3;k++){
        int idx = lane + k*64;
        if (idx < 168){
          float v;
          if (idx < 19)        v = orig[(b*19+idx)*NPTS + n];
          else if (idx < 147)  v = has ? pb[(long)(idx-19)*N0V + first] : 0.0f;
          else                 v = 0.0f;
          rowp[idx] = f2bf(v);
        }
      }
    }
  }
  __syncthreads();

  f32x4 acc;
  tile_mm<5>(xa, wt, 168, li, hi, rt, colg, acc);
  float bo = b0[colg];
  #pragma unroll
  for (int r=0;r<4;r++) acc[r] += bo;
  tile_partials(acc, slot0, blk, lane, colg);
  #pragma unroll
  for (int r=0;r<4;r++)
    y0[(long)(b*4096 + n0 + rt*16 + hi*4 + r)*128 + colg] = f2bf(acc[r]);
}

// ================= k_lmid: DMA wt + stats(prev slots) + affine + MFMA + partials + y out ======
__global__ __launch_bounds__(1024) void k_lmid(
    const ushortT* __restrict__ yin, const float* __restrict__ slotPrev,
    const float* __restrict__ g, const float* __restrict__ be,
    const ushortT* __restrict__ wpk, const float* __restrict__ bias,
    float* __restrict__ slotCur, ushortT* __restrict__ yout)
{
  __shared__ __align__(16) ushortT wt[128*136];
  __shared__ __align__(16) ushortT xa[32*168];
  __shared__ float red2[256];
  __shared__ float stS[128];
  __shared__ float stB[128];

  const int t    = threadIdx.x;
  const int blk  = blockIdx.x;
  const int lane = t & 63;
  const int w    = t >> 6;
  const int n0   = blk * 32;        // global row base 0..8191
  const int li   = lane & 15;
  const int hi   = lane >> 4;
  const int rt   = w >> 3;
  const int colg = (w & 7)*16 + li;

  dma_w(wpk, wt, 34, w, lane);                     // 34816B async; drained at syncthreads

  for (int u = t; u < 1280; u += 1024){            // zero xa pad cols 128..167
    int row = u/40, c = 128 + (u - row*40);
    xa[row*168 + c] = 0;
  }
  slot_stats(slotPrev, g, be, red2, stS, stB, t);

  if (t < 512){
    int row = t >> 4, c0 = (t & 15) * 8;
    short8 yv = *(const short8*)(yin + (long)(n0+row)*128 + c0);
    short8 xv;
    #pragma unroll
    for (int j=0;j<8;j++){
      float f = bf2f((ushortT)yv[j]);
      f = fmaxf(fmaf(f, stS[c0+j], stB[c0+j]), 0.f);
      xv[j] = (short)f2bf(f);
    }
    *(short8*)(xa + row*168 + c0) = xv;
  }
  __syncthreads();                                 // drains DMA (vmcnt 0) + xa ready

  f32x4 acc;
  tile_mm<4>(xa, wt, 136, li, hi, rt, colg, acc);
  float bo = bias[colg];
  #pragma unroll
  for (int r=0;r<4;r++) acc[r] += bo;
  tile_partials(acc, slotCur, blk, lane, colg);
  #pragma unroll
  for (int r=0;r<4;r++)
    yout[(long)(n0 + rt*16 + hi*4 + r)*128 + colg] = f2bf(acc[r]);
}

// ================= k_out: stats(L2 slots) + affine/relu + transpose + store ==================
__global__ __launch_bounds__(1024) void k_out(
    const ushortT* __restrict__ yin, const float* __restrict__ slotPrev,
    const float* __restrict__ g, const float* __restrict__ be,
    float* __restrict__ out)
{
  __shared__ float ft[32*132];
  __shared__ float red2[256];
  __shared__ float stS[128];
  __shared__ float stB[128];

  const int t   = threadIdx.x;
  const int blk = blockIdx.x;
  const int b   = blk >> 7;
  const int n0  = (blk & 127) * 32;

  slot_stats(slotPrev, g, be, red2, stS, stB, t);

  if (t < 512){
    int row = t >> 4, c0 = (t & 15) * 8;
    short8 yv = *(const short8*)(yin + (long)(b*4096 + n0 + row)*128 + c0);
    #pragma unroll
    for (int j=0;j<8;j++)
      ft[row*132 + c0 + j] = fmaxf(fmaf(bf2f((ushortT)yv[j]), stS[c0+j], stB[c0+j]), 0.f);
  }
  __syncthreads();

  float* ob = out + (long)b*128*NPTS + n0;
  {
    int oo = t >> 3, jj = (t & 7) * 4;   // 1024 threads cover 128 ch x 32 rows as float4
    float4 v;
    v.x = ft[(jj  )*132 + oo];
    v.y = ft[(jj+1)*132 + oo];
    v.z = ft[(jj+2)*132 + oo];
    v.w = ft[(jj+3)*132 + oo];
    *(float4*)(ob + (long)oo*NPTS + jj) = v;
  }
}

extern "C" void kernel_launch(void* const* d_in, const int* in_sizes, int n_in,
                              void* d_out, int out_size, void* d_ws, size_t ws_size,
                              hipStream_t stream)
{
  const float* orig   = (const float*)d_in[0];
  const float* proj   = (const float*)d_in[1];
  const float* vertex = (const float*)d_in[2];
  const int*   nidx   = (const int*)d_in[3];
  const float* W0 = (const float*)d_in[4];
  const float* b0 = (const float*)d_in[5];
  const float* g0 = (const float*)d_in[6];
  const float* be0= (const float*)d_in[7];
  const float* W1 = (const float*)d_in[8];
  const float* b1 = (const float*)d_in[9];
  const float* g1 = (const float*)d_in[10];
  const float* be1= (const float*)d_in[11];
  const float* W2 = (const float*)d_in[12];
  const float* b2 = (const float*)d_in[13];
  const float* g2 = (const float*)d_in[14];
  const float* be2= (const float*)d_in[15];
  float* out = (float*)d_out;

  float*   ws    = (float*)d_ws;
  float*   slot0 = ws;                        // 4096 floats
  float*   slot1 = ws + 4096;                 // 4096
  float*   slot2 = ws + 8192;                 // 4096 (contiguous with slot1 for slotZ)
  ushortT* wpkg  = (ushortT*)(ws + 12288);    // 34816 bf16 = 17408 floats
  ushortT* yA    = (ushortT*)(ws + 29696);    // 8192*128 bf16 = 2MB
  ushortT* yB    = yA + 8192*128;

  hipMemsetAsync(d_ws, 0, 4096*sizeof(float), stream);   // slot0 only; slot1/2 zeroed by k_l0

  k_l0  <<<256, 1024, 0, stream>>>(orig, proj, vertex, nidx, W0, b0, W1, W2,
                                   slot0, slot1, wpkg, yA);
  k_lmid<<<256, 1024, 0, stream>>>(yA, slot0, g0, be0, wpkg,         b1, slot1, yB);
  k_lmid<<<256, 1024, 0, stream>>>(yB, slot1, g1, be1, wpkg + 17408, b2, slot2, yA);
  k_out <<<256, 1024, 0, stream>>>(yA, slot2, g2, be2, out);
}